// Round 1
// baseline (188.521 us; speedup 1.0000x reference)
//
#include <hip/hip_runtime.h>

// Edge (replicate) pad, width 2 on H and W.
// In:  (32, 256, 56, 56) fp32  -> NC = 8192 planes of 56x56
// Out: (32, 256, 60, 60) fp32
//
// One thread per output float4 (row = 60 floats = 15 float4, 16B-aligned
// since row stride 240 B and plane stride 14400 B are both /16).
// Scalar clamped loads (source window is unaligned), vector store.

#define IN_H  56
#define IN_W  56
#define OUT_H 60
#define OUT_W 60
#define PAD   2

__global__ __launch_bounds__(256) void pad2d_edge_kernel(
    const float* __restrict__ in, float* __restrict__ out, int n_vec) {
    int idx = blockIdx.x * blockDim.x + threadIdx.x;
    if (idx >= n_vec) return;

    int w4 = idx % (OUT_W / 4);      // which float4 within the row
    int t  = idx / (OUT_W / 4);
    int oh = t % OUT_H;
    int nc = t / OUT_H;

    int ih = min(max(oh - PAD, 0), IN_H - 1);
    const float* src = in + (size_t)nc * (IN_H * IN_W) + (size_t)ih * IN_W;

    int ow0 = w4 * 4;
    float4 v;
    v.x = src[min(max(ow0 + 0 - PAD, 0), IN_W - 1)];
    v.y = src[min(max(ow0 + 1 - PAD, 0), IN_W - 1)];
    v.z = src[min(max(ow0 + 2 - PAD, 0), IN_W - 1)];
    v.w = src[min(max(ow0 + 3 - PAD, 0), IN_W - 1)];

    reinterpret_cast<float4*>(out)[idx] = v;
}

extern "C" void kernel_launch(void* const* d_in, const int* in_sizes, int n_in,
                              void* d_out, int out_size, void* d_ws, size_t ws_size,
                              hipStream_t stream) {
    const float* x = (const float*)d_in[0];
    float* out = (float*)d_out;

    int n_vec = out_size / 4;  // out_size = 32*256*60*60 = 29,491,200 (divisible by 4)
    int block = 256;
    int grid = (n_vec + block - 1) / block;
    pad2d_edge_kernel<<<grid, block, 0, stream>>>(x, out, n_vec);
}